// Round 6
// baseline (2745.167 us; speedup 1.0000x reference)
//
#include <hip/hip_runtime.h>
#include <stdint.h>

#define NPTS 8192
#define NBATCH 8
#define NPOINT 2048
#define KNN_K 16
#define CIN 64
#define COUT 128

typedef unsigned long long u64;
typedef unsigned int u32;

#define MAXU64(a, b) (((a) > (b)) ? (a) : (b))
#define MAXF64(a, b) fmax((a), (b))

// wave64 max-reduce of a positive-finite f64 key via DPP row_shr + row_bcast.
// Result valid in lane 63. Proven in rounds 4-5.
__device__ __forceinline__ double wave_max_f64(double v) {
#define DPPSTEP(C)                                                             \
  {                                                                            \
    u64 k = (u64)__double_as_longlong(v);                                      \
    u32 lo = (u32)k, hi = (u32)(k >> 32);                                      \
    u32 nlo = (u32)__builtin_amdgcn_update_dpp(0, (int)lo, C, 0xf, 0xf, true); \
    u32 nhi = (u32)__builtin_amdgcn_update_dpp(0, (int)hi, C, 0xf, 0xf, true); \
    double o = __longlong_as_double((long long)(((u64)nhi << 32) | nlo));      \
    v = fmax(v, o);                                                            \
  }
  DPPSTEP(0x111)
  DPPSTEP(0x112)
  DPPSTEP(0x114)
  DPPSTEP(0x118)
  DPPSTEP(0x142)
  DPPSTEP(0x143)
#undef DPPSTEP
  return v;
}

// wave64 max-reduce on exact u64 keys (for knn).
__device__ __forceinline__ u64 wave_max_u64(u64 k) {
  u32 lo = (u32)k, hi = (u32)(k >> 32);
#define DPPSTEP(C)                                                             \
  {                                                                            \
    u32 nlo = (u32)__builtin_amdgcn_update_dpp(0, (int)lo, C, 0xf, 0xf, true); \
    u32 nhi = (u32)__builtin_amdgcn_update_dpp(0, (int)hi, C, 0xf, 0xf, true); \
    u64 cur = ((u64)hi << 32) | lo;                                            \
    u64 oth = ((u64)nhi << 32) | nlo;                                          \
    if (oth > cur) { hi = nhi; lo = nlo; }                                     \
  }
  DPPSTEP(0x111)
  DPPSTEP(0x112)
  DPPSTEP(0x114)
  DPPSTEP(0x118)
  DPPSTEP(0x142)
  DPPSTEP(0x143)
#undef DPPSTEP
  return ((u64)hi << 32) | lo;
}

// wave64 min/max f32, invalid lanes keep own value (bound_ctrl=false, old=v).
__device__ __forceinline__ float wave_min_f32(float v) {
#define STEP(C)                                                                \
  {                                                                            \
    int o = __builtin_amdgcn_update_dpp((int)__float_as_uint(v),               \
                                        (int)__float_as_uint(v), C, 0xf, 0xf,  \
                                        false);                                \
    v = fminf(v, __uint_as_float((u32)o));                                     \
  }
  STEP(0x111) STEP(0x112) STEP(0x114) STEP(0x118) STEP(0x142) STEP(0x143)
#undef STEP
  return v;
}
__device__ __forceinline__ float wave_max_f32(float v) {
#define STEP(C)                                                                \
  {                                                                            \
    int o = __builtin_amdgcn_update_dpp((int)__float_as_uint(v),               \
                                        (int)__float_as_uint(v), C, 0xf, 0xf,  \
                                        false);                                \
    v = fmaxf(v, __uint_as_float((u32)o));                                     \
  }
  STEP(0x111) STEP(0x112) STEP(0x114) STEP(0x118) STEP(0x142) STEP(0x143)
#undef STEP
  return v;
}

__device__ __forceinline__ u32 spread3(u32 v) {  // 4 bits -> bits 0,3,6,9
  return (v & 1u) | ((v & 2u) << 2) | ((v & 4u) << 4) | ((v & 8u) << 6);
}

// ---------------- Kernel 1: FPS with Morton chunks + exact incremental skip --
// grid NBATCH, block 512 (8 waves). Points Morton-sorted into LDS SoA; 128
// chunks of 64 points, each with cached bbox + cached max-key (f64) + dmax.
// Per iter: test all chunks (2/lane), update only dirty ones (chunk c&7==wid),
// resolve global max over 128 cached keys. Skips are provably bit-exact.
__global__ __launch_bounds__(512) void fps_kernel(const float* __restrict__ xyz,
                                                  int* __restrict__ cent) {
  const int b = blockIdx.x;
  const int tid = threadIdx.x;
  const int lane = tid & 63;
  const int wid = tid >> 6;
  const float* xb = xyz + (size_t)b * NPTS * 3;

  __shared__ float X[NPTS], Y[NPTS], Z[NPTS];
  __shared__ float Dd[NPTS];  // dist; first 18KB doubles as cnt/tsum in sort
  __shared__ unsigned short O[NPTS];
  __shared__ __align__(16) float bboxT[6][128];
  __shared__ __align__(16) float khiT[128];
  __shared__ __align__(16) u64 keys[128];
  __shared__ float gred[8][6];
  __shared__ int t8[8];
  __shared__ int p0s;
  u32* cnt = (u32*)Dd;           // [4096]
  u32* tsum = ((u32*)Dd) + 4096; // [512]

  // ---- load 16 pts/thread, per-thread global bbox ----
  float lx[16], ly[16], lz[16];
  float gxl = 3e38f, gxh = -3e38f, gyl = 3e38f, gyh = -3e38f, gzl = 3e38f, gzh = -3e38f;
#pragma unroll
  for (int j = 0; j < 16; ++j) {
    int i = tid + 512 * j;
    float x = xb[i * 3 + 0], y = xb[i * 3 + 1], z = xb[i * 3 + 2];
    lx[j] = x; ly[j] = y; lz[j] = z;
    gxl = fminf(gxl, x); gxh = fmaxf(gxh, x);
    gyl = fminf(gyl, y); gyh = fmaxf(gyh, y);
    gzl = fminf(gzl, z); gzh = fmaxf(gzh, z);
  }
  gxl = wave_min_f32(gxl); gxh = wave_max_f32(gxh);
  gyl = wave_min_f32(gyl); gyh = wave_max_f32(gyh);
  gzl = wave_min_f32(gzl); gzh = wave_max_f32(gzh);
  if (lane == 63) {
    gred[wid][0] = gxl; gred[wid][1] = gxh; gred[wid][2] = gyl;
    gred[wid][3] = gyh; gred[wid][4] = gzl; gred[wid][5] = gzh;
  }
  // zero cnt while the reduce settles
  __syncthreads();
  float gx0 = gred[0][0], gx1 = gred[0][1], gy0 = gred[0][2];
  float gy1 = gred[0][3], gz0 = gred[0][4], gz1 = gred[0][5];
#pragma unroll
  for (int w = 1; w < 8; ++w) {
    gx0 = fminf(gx0, gred[w][0]); gx1 = fmaxf(gx1, gred[w][1]);
    gy0 = fminf(gy0, gred[w][2]); gy1 = fmaxf(gy1, gred[w][3]);
    gz0 = fminf(gz0, gred[w][4]); gz1 = fmaxf(gz1, gred[w][5]);
  }
  const float sx = 16.f / fmaxf((gx1 - gx0) * 1.0001f, 1e-20f);
  const float sy = 16.f / fmaxf((gy1 - gy0) * 1.0001f, 1e-20f);
  const float sz = 16.f / fmaxf((gz1 - gz0) * 1.0001f, 1e-20f);
#pragma unroll
  for (int k = 0; k < 8; ++k) cnt[tid * 8 + k] = 0;
  __syncthreads();

  // ---- morton codes + histogram ----
  u32 mc[16];
#pragma unroll
  for (int j = 0; j < 16; ++j) {
    int qx = min(15, max(0, (int)((lx[j] - gx0) * sx)));
    int qy = min(15, max(0, (int)((ly[j] - gy0) * sy)));
    int qz = min(15, max(0, (int)((lz[j] - gz0) * sz)));
    mc[j] = (spread3((u32)qx) << 2) | (spread3((u32)qy) << 1) | spread3((u32)qz);
    atomicAdd(&cnt[mc[j]], 1);
  }
  __syncthreads();
  // ---- exclusive prefix sum over 4096 bins ----
  {
    u32 s = 0;
#pragma unroll
    for (int k = 0; k < 8; ++k) { u32 c = cnt[tid * 8 + k]; cnt[tid * 8 + k] = s; s += c; }
    tsum[tid] = s;
  }
  __syncthreads();
  if (tid < 8) {
    u32 s = 0;
    for (int k = 0; k < 64; ++k) { u32 c = tsum[tid * 64 + k]; tsum[tid * 64 + k] = s; s += c; }
    t8[tid] = (int)s;
  }
  __syncthreads();
  if (tid == 0) {
    int s = 0;
#pragma unroll
    for (int k = 0; k < 8; ++k) { int c = t8[k]; t8[k] = s; s += c; }
  }
  __syncthreads();
  {
    u32 base = tsum[tid] + (u32)t8[tid >> 6];
#pragma unroll
    for (int k = 0; k < 8; ++k) cnt[tid * 8 + k] += base;
  }
  __syncthreads();
  // ---- scatter into sorted SoA ----
#pragma unroll
  for (int j = 0; j < 16; ++j) {
    int i = tid + 512 * j;
    u32 pos = atomicAdd(&cnt[mc[j]], 1);
    X[pos] = lx[j]; Y[pos] = ly[j]; Z[pos] = lz[j];
    O[pos] = (unsigned short)i;
    if (i == 0) p0s = (int)pos;
  }
  if (tid == 0) cent[b * NPOINT] = 0;
  __syncthreads();
  // ---- per-chunk bbox (wave w owns chunks w*16..w*16+15) + init D/keys ----
  for (int r = 0; r < 16; ++r) {
    int c = wid * 16 + r;
    int p = c * 64 + lane;
    float x = X[p], y = Y[p], z = Z[p];
    float xl = wave_min_f32(x), xh = wave_max_f32(x);
    float yl = wave_min_f32(y), yh = wave_max_f32(y);
    float zl = wave_min_f32(z), zh = wave_max_f32(z);
    if (lane == 63) {
      bboxT[0][c] = xl; bboxT[1][c] = xh; bboxT[2][c] = yl;
      bboxT[3][c] = yh; bboxT[4][c] = zl; bboxT[5][c] = zh;
    }
  }
#pragma unroll
  for (int j = 0; j < 16; ++j) Dd[tid + 512 * j] = 1e10f;
  if (tid < 128) {
    khiT[tid] = 1e10f;
    keys[tid] = ((u64)__float_as_uint(1e10f) << 32);
  }
  __syncthreads();

  float cx = X[p0s], cy = Y[p0s], cz = Z[p0s];

#define PROCESS_CHUNK(c)                                                       \
  {                                                                            \
    int p = (c)*64 + lane;                                                     \
    float x = X[p], y = Y[p], z = Z[p];                                        \
    float dc = Dd[p];                                                          \
    u32 o = (u32)O[p];                                                         \
    float dx = x - cx, dy = y - cy, dz = z - cz;                               \
    float dd = dx * dx + dy * dy + dz * dz; /* same expr as rounds 1-5 */      \
    float t = fminf(dc, dd);                                                   \
    Dd[p] = t;                                                                 \
    u32 klo = ((8191u - o) << 13) | (u32)p;                                    \
    double k = __longlong_as_double(                                           \
        (long long)(((u64)__float_as_uint(t) << 32) | klo));                   \
    k = wave_max_f64(k);                                                       \
    if (lane == 63) {                                                          \
      u64 kb = (u64)__double_as_longlong(k);                                   \
      keys[c] = kb;                                                            \
      khiT[c] = __uint_as_float((u32)(kb >> 32));                              \
    }                                                                          \
  }

  for (int it = 1; it < NPOINT; ++it) {
    // ---- A: test chunks 2*lane, 2*lane+1; claim mine via c&7==wid ----
    const int c0 = 2 * lane;
    float2 bxl = *(const float2*)&bboxT[0][c0];
    float2 bxh = *(const float2*)&bboxT[1][c0];
    float2 byl = *(const float2*)&bboxT[2][c0];
    float2 byh = *(const float2*)&bboxT[3][c0];
    float2 bzl = *(const float2*)&bboxT[4][c0];
    float2 bzh = *(const float2*)&bboxT[5][c0];
    float2 kh = *(const float2*)&khiT[c0];
    float ax = fmaxf(fmaxf(bxl.x - cx, cx - bxh.x), 0.f);
    float ay = fmaxf(fmaxf(byl.x - cy, cy - byh.x), 0.f);
    float az = fmaxf(fmaxf(bzl.x - cz, cz - bzh.x), 0.f);
    float LB0 = ax * ax + ay * ay + az * az;
    ax = fmaxf(fmaxf(bxl.y - cx, cx - bxh.y), 0.f);
    ay = fmaxf(fmaxf(byl.y - cy, cy - byh.y), 0.f);
    az = fmaxf(fmaxf(bzl.y - cz, cz - bzh.y), 0.f);
    float LB1 = ax * ax + ay * ay + az * az;
    bool mine0 = !(LB0 > kh.x * 1.00002f) && ((c0 & 7) == wid);
    bool mine1 = !(LB1 > kh.y * 1.00002f) && (((c0 + 1) & 7) == wid);
    u64 mA = __ballot(mine0);
    u64 mB = __ballot(mine1);
    __syncthreads();
    // ---- B: update my dirty chunks ----
    while (mA) { int l2 = __ffsll(mA) - 1; mA &= mA - 1; PROCESS_CHUNK(2 * l2); }
    while (mB) { int l2 = __ffsll(mB) - 1; mB &= mB - 1; PROCESS_CHUNK(2 * l2 + 1); }
    __syncthreads();
    // ---- C: resolve global max over 128 cached keys ----
    double2 kk = *(const double2*)&keys[c0];
    double mk = MAXF64(kk.x, kk.y);
    mk = wave_max_f64(mk);
    u32 lo = (u32)(u64)__double_as_longlong(mk);
    lo = (u32)__builtin_amdgcn_readlane((int)lo, 63);
    u32 pos = lo & 8191u;
    if (tid == 0) cent[b * NPOINT + it] = (int)(8191u - ((lo >> 13) & 8191u));
    cx = X[pos]; cy = Y[pos]; cz = Z[pos];  // broadcast LDS reads
  }
#undef PROCESS_CHUNK
}

// ---------------- Kernel 2: 16-NN per centroid + new_xyz gather ----------------
__global__ __launch_bounds__(256) void knn_kernel(const float* __restrict__ xyz,
                                                  const int* __restrict__ cent,
                                                  int* __restrict__ knn,
                                                  float* __restrict__ out_xyz) {
  const int pt = blockIdx.x;       // 0..16383
  const int b = pt >> 11;
  const int tid = threadIdx.x;
  const float* xb = xyz + (size_t)b * NPTS * 3;
  const int ci = cent[pt];
  const float mx = xb[ci * 3 + 0], my = xb[ci * 3 + 1], mz = xb[ci * 3 + 2];
  if (tid < 3) out_xyz[pt * 3 + tid] = xb[ci * 3 + tid];
  const float sm = mx * mx + my * my + mz * mz;

  float d[32];
  float lv = 3.0e38f;
  int lj = 0;
#pragma unroll
  for (int j = 0; j < 32; ++j) {
    int i = tid + 256 * j;
    float x = xb[i * 3 + 0], y = xb[i * 3 + 1], z = xb[i * 3 + 2];
    float dot = mx * x + my * y + mz * z;
    float sp = x * x + y * y + z * z;
    float dd = -2.0f * dot + sm + sp;   // same assoc as reference
    d[j] = dd;
    if (dd < lv) { lv = dd; lj = j; }
  }

  __shared__ __align__(16) u64 kbuf[2][4];
  const int lane = tid & 63;

  for (int p = 0; p < KNN_K; ++p) {
    u32 fb = __float_as_uint(lv);
    u32 mapped = (fb & 0x80000000u) ? ~fb : (fb | 0x80000000u);
    u32 idx = (u32)(tid + (lj << 8));
    u64 ik = ~(((u64)mapped << 32) | (u64)idx);
    u64 wk = wave_max_u64(ik);
    if (lane == 63) kbuf[p & 1][tid >> 6] = wk;
    __syncthreads();
    const ulonglong2* kb = (const ulonglong2*)&kbuf[p & 1][0];
    ulonglong2 q0 = kb[0], q1 = kb[1];
    u64 best = MAXU64(MAXU64(q0.x, q0.y), MAXU64(q1.x, q1.y));
    u32 widx = (u32)(~best);
    if (tid == 0) knn[pt * KNN_K + p] = (int)widx;
    if (tid == (int)(widx & 255u)) {
      int j0 = (int)(widx >> 8);
      float nlv = 3.0e38f;
      int nlj = 0;
#pragma unroll
      for (int j = 0; j < 32; ++j) {
        if (j == j0) d[j] = 3.0e38f;
        if (d[j] < nlv) { nlv = d[j]; nlj = j; }
      }
      lv = nlv; lj = nlj;
    }
  }
}

// ---------------- Kernel 3: gather+GEMM + BN partials + per-(pt,o) max/min ----------------
__global__ __launch_bounds__(256) void gemm_stats_kernel(const float* __restrict__ feat,
                                                         const float* __restrict__ W,
                                                         const int* __restrict__ knn,
                                                         float* __restrict__ part,
                                                         float* __restrict__ mxbuf,
                                                         float* __restrict__ mnbuf) {
  const int tid = threadIdx.x;
  const int o0 = (tid & 63) * 2;
  const int o1 = o0 + 1;
  const int grp = tid >> 6;
  __shared__ __align__(16) float g[128][CIN];
  __shared__ int kidx[128];
  __shared__ float sred[4][128];

  const int rowbase = blockIdx.x * 128;
  if (tid < 128) kidx[tid] = knn[rowbase + tid];

  float4 w0v[16], w1v[16];
  {
    const float4* wv0 = (const float4*)(W + (size_t)o0 * CIN);
    const float4* wv1 = (const float4*)(W + (size_t)o1 * CIN);
#pragma unroll
    for (int q = 0; q < 16; ++q) { w0v[q] = wv0[q]; w1v[q] = wv1[q]; }
  }
  __syncthreads();
#pragma unroll
  for (int s = 0; s < 8; ++s) {
    int v = tid + 256 * s;
    int row = v >> 4, q = v & 15;
    int gr = rowbase + row;
    int bb = gr >> 15;
    const float4* src = (const float4*)(feat + (size_t)(bb * NPTS + kidx[row]) * CIN);
    *((float4*)&g[row][q * 4]) = src[q];
  }
  __syncthreads();

  float s1_0 = 0.f, s2_0 = 0.f, s1_1 = 0.f, s2_1 = 0.f;
#pragma unroll
  for (int pp = 0; pp < 2; ++pp) {
    const int ptl = grp + pp * 4;
    float mx0 = -3.0e38f, mn0 = 3.0e38f, mx1 = -3.0e38f, mn1 = 3.0e38f;
#pragma unroll
    for (int k = 0; k < KNN_K; ++k) {
      const int row = ptl * 16 + k;
      float a0 = 0.f, a1 = 0.f;
#pragma unroll
      for (int q = 0; q < 16; ++q) {
        float4 a = *((const float4*)&g[row][q * 4]);
        a0 += w0v[q].x * a.x + w0v[q].y * a.y + w0v[q].z * a.z + w0v[q].w * a.w;
        a1 += w1v[q].x * a.x + w1v[q].y * a.y + w1v[q].z * a.z + w1v[q].w * a.w;
      }
      s1_0 += a0; s2_0 += a0 * a0; mx0 = fmaxf(mx0, a0); mn0 = fminf(mn0, a0);
      s1_1 += a1; s2_1 += a1 * a1; mx1 = fmaxf(mx1, a1); mn1 = fminf(mn1, a1);
    }
    const size_t pt = (size_t)blockIdx.x * 8 + ptl;
    mxbuf[pt * COUT + o0] = mx0;
    mxbuf[pt * COUT + o1] = mx1;
    mnbuf[pt * COUT + o0] = mn0;
    mnbuf[pt * COUT + o1] = mn1;
  }
  sred[grp][o0] = s1_0; sred[grp][o1] = s1_1;
  __syncthreads();
  if (tid < 128) {
    float t = sred[0][tid] + sred[1][tid] + sred[2][tid] + sred[3][tid];
    part[blockIdx.x * 256 + tid] = t;
  }
  __syncthreads();
  sred[grp][o0] = s2_0; sred[grp][o1] = s2_1;
  __syncthreads();
  if (tid < 128) {
    float t = sred[0][tid] + sred[1][tid] + sred[2][tid] + sred[3][tid];
    part[blockIdx.x * 256 + 128 + tid] = t;
  }
}

// ---------------- Kernel 4: reduce partials -> scale/shift per channel ----------------
__global__ __launch_bounds__(256) void bn_reduce_kernel(const float* __restrict__ part,
                                                        const float* __restrict__ gamma,
                                                        const float* __restrict__ beta,
                                                        float* __restrict__ stats) {
  const int o = blockIdx.x;
  const int tid = threadIdx.x;
  float s1 = 0.f, s2 = 0.f;
  for (int p = tid; p < 2048; p += 256) {
    s1 += part[p * 256 + o];
    s2 += part[p * 256 + 128 + o];
  }
  __shared__ float r1[256], r2[256];
  r1[tid] = s1; r2[tid] = s2;
  __syncthreads();
  for (int s = 128; s >= 1; s >>= 1) {
    if (tid < s) { r1[tid] += r1[tid + s]; r2[tid] += r2[tid + s]; }
    __syncthreads();
  }
  if (tid == 0) {
    const float n = (float)(NBATCH * NPOINT * KNN_K);
    float mean = r1[0] / n;
    float var = r2[0] / n - mean * mean;
    float inv = rsqrtf(var + 1e-5f);
    float sc = gamma[o] * inv;
    stats[o] = sc;
    stats[128 + o] = beta[o] - mean * sc;
  }
}

// ---------------- Kernel 5: finalize out = relu(sel*sc + sh) ----------------
__global__ __launch_bounds__(256) void finalize_kernel(float* __restrict__ out_feat,
                                                       const float* __restrict__ mnbuf,
                                                       const float* __restrict__ stats) {
  const int i = blockIdx.x * 256 + threadIdx.x;
  const int o = i & 127;
  const float sc = stats[o];
  const float sh = stats[128 + o];
  const float mx = out_feat[i];
  const float mn = mnbuf[i];
  const float sel = (sc >= 0.f) ? mx : mn;
  out_feat[i] = fmaxf(sel * sc + sh, 0.f);
}

extern "C" void kernel_launch(void* const* d_in, const int* in_sizes, int n_in,
                              void* d_out, int out_size, void* d_ws, size_t ws_size,
                              hipStream_t stream) {
  const float* xyz = (const float*)d_in[0];
  const float* feat = (const float*)d_in[1];
  const float* W = (const float*)d_in[2];
  const float* gamma = (const float*)d_in[3];
  const float* beta = (const float*)d_in[4];
  float* out = (float*)d_out;

  int* cent = (int*)d_ws;
  int* knn = cent + NBATCH * NPOINT;
  float* part = (float*)(knn + NBATCH * NPOINT * KNN_K);
  float* stats = part + 2048 * 256;
  float* mnbuf = stats + 256;

  float* out_xyz = out;
  float* out_feat = out + NBATCH * NPOINT * 3;

  hipLaunchKernelGGL(fps_kernel, dim3(NBATCH), dim3(512), 0, stream, xyz, cent);
  hipLaunchKernelGGL(knn_kernel, dim3(NBATCH * NPOINT), dim3(256), 0, stream,
                     xyz, cent, knn, out_xyz);
  hipLaunchKernelGGL(gemm_stats_kernel, dim3(2048), dim3(256), 0, stream,
                     feat, W, knn, part, out_feat, mnbuf);
  hipLaunchKernelGGL(bn_reduce_kernel, dim3(128), dim3(256), 0, stream,
                     part, gamma, beta, stats);
  hipLaunchKernelGGL(finalize_kernel, dim3(8192), dim3(256), 0, stream,
                     out_feat, mnbuf, stats);
}

// Round 7
// 2146.516 us; speedup vs baseline: 1.2789x; 1.2789x over previous
//
#include <hip/hip_runtime.h>
#include <stdint.h>

#define NPTS 8192
#define NBATCH 8
#define NPOINT 2048
#define KNN_K 16
#define CIN 64
#define COUT 128

typedef unsigned long long u64;
typedef unsigned int u32;

#define MAXU64(a, b) (((a) > (b)) ? (a) : (b))
#define MAXF64(a, b) fmax((a), (b))

// wave64 max-reduce of a positive-finite f64 key via DPP row_shr + row_bcast.
// Result valid in lane 63. Proven in rounds 4-6.
__device__ __forceinline__ double wave_max_f64(double v) {
#define DPPSTEP(C)                                                             \
  {                                                                            \
    u64 k = (u64)__double_as_longlong(v);                                      \
    u32 lo = (u32)k, hi = (u32)(k >> 32);                                      \
    u32 nlo = (u32)__builtin_amdgcn_update_dpp(0, (int)lo, C, 0xf, 0xf, true); \
    u32 nhi = (u32)__builtin_amdgcn_update_dpp(0, (int)hi, C, 0xf, 0xf, true); \
    double o = __longlong_as_double((long long)(((u64)nhi << 32) | nlo));      \
    v = fmax(v, o);                                                            \
  }
  DPPSTEP(0x111)
  DPPSTEP(0x112)
  DPPSTEP(0x114)
  DPPSTEP(0x118)
  DPPSTEP(0x142)
  DPPSTEP(0x143)
#undef DPPSTEP
  return v;
}

// 16-lane row max of positive-finite f64 (each 16-lane row reduces its own
// values); result valid in lane 15 of each row.
__device__ __forceinline__ double row16_max_f64(double v) {
#define DPPSTEP(C)                                                             \
  {                                                                            \
    u64 k = (u64)__double_as_longlong(v);                                      \
    u32 lo = (u32)k, hi = (u32)(k >> 32);                                      \
    u32 nlo = (u32)__builtin_amdgcn_update_dpp(0, (int)lo, C, 0xf, 0xf, true); \
    u32 nhi = (u32)__builtin_amdgcn_update_dpp(0, (int)hi, C, 0xf, 0xf, true); \
    double o = __longlong_as_double((long long)(((u64)nhi << 32) | nlo));      \
    v = fmax(v, o);                                                            \
  }
  DPPSTEP(0x111)
  DPPSTEP(0x112)
  DPPSTEP(0x114)
  DPPSTEP(0x118)
#undef DPPSTEP
  return v;
}

// wave64 max-reduce on exact u64 keys (for knn).
__device__ __forceinline__ u64 wave_max_u64(u64 k) {
  u32 lo = (u32)k, hi = (u32)(k >> 32);
#define DPPSTEP(C)                                                             \
  {                                                                            \
    u32 nlo = (u32)__builtin_amdgcn_update_dpp(0, (int)lo, C, 0xf, 0xf, true); \
    u32 nhi = (u32)__builtin_amdgcn_update_dpp(0, (int)hi, C, 0xf, 0xf, true); \
    u64 cur = ((u64)hi << 32) | lo;                                            \
    u64 oth = ((u64)nhi << 32) | nlo;                                          \
    if (oth > cur) { hi = nhi; lo = nlo; }                                     \
  }
  DPPSTEP(0x111)
  DPPSTEP(0x112)
  DPPSTEP(0x114)
  DPPSTEP(0x118)
  DPPSTEP(0x142)
  DPPSTEP(0x143)
#undef DPPSTEP
  return ((u64)hi << 32) | lo;
}

// wave64 min/max f32, invalid lanes keep own value (bound_ctrl=false).
__device__ __forceinline__ float wave_min_f32(float v) {
#define STEP(C)                                                                \
  {                                                                            \
    int o = __builtin_amdgcn_update_dpp((int)__float_as_uint(v),               \
                                        (int)__float_as_uint(v), C, 0xf, 0xf,  \
                                        false);                                \
    v = fminf(v, __uint_as_float((u32)o));                                     \
  }
  STEP(0x111) STEP(0x112) STEP(0x114) STEP(0x118) STEP(0x142) STEP(0x143)
#undef STEP
  return v;
}
__device__ __forceinline__ float wave_max_f32(float v) {
#define STEP(C)                                                                \
  {                                                                            \
    int o = __builtin_amdgcn_update_dpp((int)__float_as_uint(v),               \
                                        (int)__float_as_uint(v), C, 0xf, 0xf,  \
                                        false);                                \
    v = fmaxf(v, __uint_as_float((u32)o));                                     \
  }
  STEP(0x111) STEP(0x112) STEP(0x114) STEP(0x118) STEP(0x142) STEP(0x143)
#undef STEP
  return v;
}

__device__ __forceinline__ float bcast63(float v) {
  return __uint_as_float(
      (u32)__builtin_amdgcn_readlane((int)__float_as_uint(v), 63));
}

// ---------------- Kernel 1: FPS, 16 waves, register-resident buckets --------
// grid NBATCH, block 1024 (16 waves). One-time: counting-sort points into 16
// spatial bins (2b x, 1b y, 1b z); wave w owns sorted slice [512w,512w+512)
// held in REGISTERS (8 pts/thread) with its true bbox. Per iter: wave-local
// bbox skip test (provably bit-exact no-op skip, margin covers f32 rounding),
// update own 8 pts if dirty, DPP f64 reduce, post key; resolve = each lane
// reads one of 16 keys + 4-step row DPP + readlane. Key =
// (dist_bits<<32)|((8191-orig)<<13)|pos : argmax with first-orig-index
// tie-break, pos bits only used to fetch coords (never affect winner choice).
__global__ __launch_bounds__(1024) void fps_kernel(const float* __restrict__ xyz,
                                                   int* __restrict__ cent) {
  const int b = blockIdx.x;
  const int tid = threadIdx.x;
  const int lane = tid & 63;
  const int wid = tid >> 6;  // 0..15
  const float* xb = xyz + (size_t)b * NPTS * 3;

  __shared__ float X[NPTS], Y[NPTS], Z[NPTS];
  __shared__ unsigned short O[NPTS];
  __shared__ float gred[16][6];
  __shared__ int cnt16[16], base16[16], cur16[16];
  __shared__ __align__(16) u64 kbuf[2][16];

  // ---- load 8 pts/thread + global bbox ----
  float lx[8], ly[8], lz[8];
  float xl = 3e38f, xh = -3e38f, yl = 3e38f, yh = -3e38f, zl = 3e38f, zh = -3e38f;
#pragma unroll
  for (int j = 0; j < 8; ++j) {
    int i = tid + 1024 * j;
    float x = xb[i * 3 + 0], y = xb[i * 3 + 1], z = xb[i * 3 + 2];
    lx[j] = x; ly[j] = y; lz[j] = z;
    xl = fminf(xl, x); xh = fmaxf(xh, x);
    yl = fminf(yl, y); yh = fmaxf(yh, y);
    zl = fminf(zl, z); zh = fmaxf(zh, z);
  }
  xl = wave_min_f32(xl); xh = wave_max_f32(xh);
  yl = wave_min_f32(yl); yh = wave_max_f32(yh);
  zl = wave_min_f32(zl); zh = wave_max_f32(zh);
  if (lane == 63) {
    gred[wid][0] = xl; gred[wid][1] = xh; gred[wid][2] = yl;
    gred[wid][3] = yh; gred[wid][4] = zl; gred[wid][5] = zh;
  }
  if (tid < 16) { cnt16[tid] = 0; cur16[tid] = 0; }
  __syncthreads();
  float gx0 = gred[0][0], gx1 = gred[0][1], gy0 = gred[0][2];
  float gy1 = gred[0][3], gz0 = gred[0][4], gz1 = gred[0][5];
#pragma unroll
  for (int w = 1; w < 16; ++w) {
    gx0 = fminf(gx0, gred[w][0]); gx1 = fmaxf(gx1, gred[w][1]);
    gy0 = fminf(gy0, gred[w][2]); gy1 = fmaxf(gy1, gred[w][3]);
    gz0 = fminf(gz0, gred[w][4]); gz1 = fmaxf(gz1, gred[w][5]);
  }
  const float sx = 4.f / fmaxf((gx1 - gx0) * 1.0001f, 1e-20f);
  const float sy = 2.f / fmaxf((gy1 - gy0) * 1.0001f, 1e-20f);
  const float sz = 2.f / fmaxf((gz1 - gz0) * 1.0001f, 1e-20f);

  // ---- 16-bin histogram ----
  int bin[8];
#pragma unroll
  for (int j = 0; j < 8; ++j) {
    int qx = min(3, max(0, (int)((lx[j] - gx0) * sx)));
    int qy = min(1, max(0, (int)((ly[j] - gy0) * sy)));
    int qz = min(1, max(0, (int)((lz[j] - gz0) * sz)));
    bin[j] = (qx << 2) | (qy << 1) | qz;
    atomicAdd(&cnt16[bin[j]], 1);
  }
  __syncthreads();
  if (tid == 0) {
    int s = 0;
#pragma unroll
    for (int k = 0; k < 16; ++k) { base16[k] = s; s += cnt16[k]; }
  }
  __syncthreads();
  // ---- scatter ----
#pragma unroll
  for (int j = 0; j < 8; ++j) {
    int i = tid + 1024 * j;
    int pos = base16[bin[j]] + atomicAdd(&cur16[bin[j]], 1);
    X[pos] = lx[j]; Y[pos] = ly[j]; Z[pos] = lz[j];
    O[pos] = (unsigned short)i;
  }
  if (tid == 0) cent[b * NPOINT] = 0;
  __syncthreads();

  // ---- own bucket into registers + wave bbox ----
  float px[8], py[8], pz[8], dist[8];
  u32 klo[8];
  float bxl = 3e38f, bxh = -3e38f, byl = 3e38f, byh = -3e38f, bzl = 3e38f, bzh = -3e38f;
#pragma unroll
  for (int j = 0; j < 8; ++j) {
    int p = wid * 512 + lane + 64 * j;
    float x = X[p], y = Y[p], z = Z[p];
    u32 orig = (u32)O[p];
    px[j] = x; py[j] = y; pz[j] = z;
    dist[j] = 1e10f;
    klo[j] = ((8191u - orig) << 13) | (u32)p;
    bxl = fminf(bxl, x); bxh = fmaxf(bxh, x);
    byl = fminf(byl, y); byh = fmaxf(byh, y);
    bzl = fminf(bzl, z); bzh = fmaxf(bzh, z);
  }
  const float bx0 = bcast63(wave_min_f32(bxl)), bx1 = bcast63(wave_max_f32(bxh));
  const float by0 = bcast63(wave_min_f32(byl)), by1 = bcast63(wave_max_f32(byh));
  const float bz0 = bcast63(wave_min_f32(bzl)), bz1 = bcast63(wave_max_f32(bzh));

  float cx = xb[0], cy = xb[1], cz = xb[2];  // centroid 0 = point 0
  float dmax = 1e10f;
  double prev_wk = 0.0;

  for (int it = 1; it < NPOINT; ++it) {
    // wave-local exact skip test
    float ax = fmaxf(fmaxf(bx0 - cx, cx - bx1), 0.f);
    float ay = fmaxf(fmaxf(by0 - cy, cy - by1), 0.f);
    float az = fmaxf(fmaxf(bz0 - cz, cz - bz1), 0.f);
    float LB = ax * ax + ay * ay + az * az;
    int skip = (LB > dmax * 1.00002f) ? 1 : 0;
    skip = __builtin_amdgcn_readfirstlane(skip);
    double wk;
    if (skip) {
      wk = prev_wk;  // bit-exact: min-update provably a no-op for this bucket
    } else {
      double key[8];
#pragma unroll
      for (int j = 0; j < 8; ++j) {
        float dx = px[j] - cx, dy = py[j] - cy, dz = pz[j] - cz;
        float dd = dx * dx + dy * dy + dz * dz;  // same expr as rounds 1-6
        float t = fminf(dist[j], dd);
        dist[j] = t;
        key[j] = __longlong_as_double(
            (long long)(((u64)__float_as_uint(t) << 32) | klo[j]));
      }
#pragma unroll
      for (int s = 1; s < 8; s <<= 1) {
#pragma unroll
        for (int j = 0; j < 8; j += 2 * s) key[j] = MAXF64(key[j], key[j + s]);
      }
      wk = wave_max_f64(key[0]);  // lane 63 owns the wave max
      prev_wk = wk;
    }
    if (lane == 63) kbuf[it & 1][wid] = (u64)__double_as_longlong(wk);
    // refresh wave-uniform dmax from own key (no LDS round-trip)
    dmax = __uint_as_float((u32)__builtin_amdgcn_readlane(
        (int)(u32)(((u64)__double_as_longlong(wk)) >> 32), 63));
    __syncthreads();  // the only barrier per iteration
    // resolve: lane reads one of 16 keys, 4-step row DPP, broadcast lane 15
    double kv = __longlong_as_double((long long)kbuf[it & 1][lane & 15]);
    kv = row16_max_f64(kv);
    u32 rlo = (u32)__builtin_amdgcn_readlane(
        (int)(u32)(u64)__double_as_longlong(kv), 15);
    u32 pos = rlo & 8191u;
    if (tid == 0) cent[b * NPOINT + it] = (int)(8191u - ((rlo >> 13) & 8191u));
    cx = X[pos]; cy = Y[pos]; cz = Z[pos];  // broadcast LDS reads
  }
}

// ---------------- Kernel 2: 16-NN per centroid + new_xyz gather ----------------
__global__ __launch_bounds__(256) void knn_kernel(const float* __restrict__ xyz,
                                                  const int* __restrict__ cent,
                                                  int* __restrict__ knn,
                                                  float* __restrict__ out_xyz) {
  const int pt = blockIdx.x;       // 0..16383
  const int b = pt >> 11;
  const int tid = threadIdx.x;
  const float* xb = xyz + (size_t)b * NPTS * 3;
  const int ci = cent[pt];
  const float mx = xb[ci * 3 + 0], my = xb[ci * 3 + 1], mz = xb[ci * 3 + 2];
  if (tid < 3) out_xyz[pt * 3 + tid] = xb[ci * 3 + tid];
  const float sm = mx * mx + my * my + mz * mz;

  float d[32];
  float lv = 3.0e38f;
  int lj = 0;
#pragma unroll
  for (int j = 0; j < 32; ++j) {
    int i = tid + 256 * j;
    float x = xb[i * 3 + 0], y = xb[i * 3 + 1], z = xb[i * 3 + 2];
    float dot = mx * x + my * y + mz * z;
    float sp = x * x + y * y + z * z;
    float dd = -2.0f * dot + sm + sp;   // same assoc as reference
    d[j] = dd;
    if (dd < lv) { lv = dd; lj = j; }
  }

  __shared__ __align__(16) u64 kbuf[2][4];
  const int lane = tid & 63;

  for (int p = 0; p < KNN_K; ++p) {
    u32 fb = __float_as_uint(lv);
    u32 mapped = (fb & 0x80000000u) ? ~fb : (fb | 0x80000000u);
    u32 idx = (u32)(tid + (lj << 8));
    u64 ik = ~(((u64)mapped << 32) | (u64)idx);
    u64 wk = wave_max_u64(ik);
    if (lane == 63) kbuf[p & 1][tid >> 6] = wk;
    __syncthreads();
    const ulonglong2* kb = (const ulonglong2*)&kbuf[p & 1][0];
    ulonglong2 q0 = kb[0], q1 = kb[1];
    u64 best = MAXU64(MAXU64(q0.x, q0.y), MAXU64(q1.x, q1.y));
    u32 widx = (u32)(~best);
    if (tid == 0) knn[pt * KNN_K + p] = (int)widx;
    if (tid == (int)(widx & 255u)) {
      int j0 = (int)(widx >> 8);
      float nlv = 3.0e38f;
      int nlj = 0;
#pragma unroll
      for (int j = 0; j < 32; ++j) {
        if (j == j0) d[j] = 3.0e38f;
        if (d[j] < nlv) { nlv = d[j]; nlj = j; }
      }
      lv = nlv; lj = nlj;
    }
  }
}

// ---------------- Kernel 3: gather+GEMM + BN partials + per-(pt,o) max/min ----------------
__global__ __launch_bounds__(256) void gemm_stats_kernel(const float* __restrict__ feat,
                                                         const float* __restrict__ W,
                                                         const int* __restrict__ knn,
                                                         float* __restrict__ part,
                                                         float* __restrict__ mxbuf,
                                                         float* __restrict__ mnbuf) {
  const int tid = threadIdx.x;
  const int o0 = (tid & 63) * 2;
  const int o1 = o0 + 1;
  const int grp = tid >> 6;
  __shared__ __align__(16) float g[128][CIN];
  __shared__ int kidx[128];
  __shared__ float sred[4][128];

  const int rowbase = blockIdx.x * 128;
  if (tid < 128) kidx[tid] = knn[rowbase + tid];

  float4 w0v[16], w1v[16];
  {
    const float4* wv0 = (const float4*)(W + (size_t)o0 * CIN);
    const float4* wv1 = (const float4*)(W + (size_t)o1 * CIN);
#pragma unroll
    for (int q = 0; q < 16; ++q) { w0v[q] = wv0[q]; w1v[q] = wv1[q]; }
  }
  __syncthreads();
#pragma unroll
  for (int s = 0; s < 8; ++s) {
    int v = tid + 256 * s;
    int row = v >> 4, q = v & 15;
    int gr = rowbase + row;
    int bb = gr >> 15;
    const float4* src = (const float4*)(feat + (size_t)(bb * NPTS + kidx[row]) * CIN);
    *((float4*)&g[row][q * 4]) = src[q];
  }
  __syncthreads();

  float s1_0 = 0.f, s2_0 = 0.f, s1_1 = 0.f, s2_1 = 0.f;
#pragma unroll
  for (int pp = 0; pp < 2; ++pp) {
    const int ptl = grp + pp * 4;
    float mx0 = -3.0e38f, mn0 = 3.0e38f, mx1 = -3.0e38f, mn1 = 3.0e38f;
#pragma unroll
    for (int k = 0; k < KNN_K; ++k) {
      const int row = ptl * 16 + k;
      float a0 = 0.f, a1 = 0.f;
#pragma unroll
      for (int q = 0; q < 16; ++q) {
        float4 a = *((const float4*)&g[row][q * 4]);
        a0 += w0v[q].x * a.x + w0v[q].y * a.y + w0v[q].z * a.z + w0v[q].w * a.w;
        a1 += w1v[q].x * a.x + w1v[q].y * a.y + w1v[q].z * a.z + w1v[q].w * a.w;
      }
      s1_0 += a0; s2_0 += a0 * a0; mx0 = fmaxf(mx0, a0); mn0 = fminf(mn0, a0);
      s1_1 += a1; s2_1 += a1 * a1; mx1 = fmaxf(mx1, a1); mn1 = fminf(mn1, a1);
    }
    const size_t pt = (size_t)blockIdx.x * 8 + ptl;
    mxbuf[pt * COUT + o0] = mx0;
    mxbuf[pt * COUT + o1] = mx1;
    mnbuf[pt * COUT + o0] = mn0;
    mnbuf[pt * COUT + o1] = mn1;
  }
  sred[grp][o0] = s1_0; sred[grp][o1] = s1_1;
  __syncthreads();
  if (tid < 128) {
    float t = sred[0][tid] + sred[1][tid] + sred[2][tid] + sred[3][tid];
    part[blockIdx.x * 256 + tid] = t;
  }
  __syncthreads();
  sred[grp][o0] = s2_0; sred[grp][o1] = s2_1;
  __syncthreads();
  if (tid < 128) {
    float t = sred[0][tid] + sred[1][tid] + sred[2][tid] + sred[3][tid];
    part[blockIdx.x * 256 + 128 + tid] = t;
  }
}

// ---------------- Kernel 4: reduce partials -> scale/shift per channel ----------------
__global__ __launch_bounds__(256) void bn_reduce_kernel(const float* __restrict__ part,
                                                        const float* __restrict__ gamma,
                                                        const float* __restrict__ beta,
                                                        float* __restrict__ stats) {
  const int o = blockIdx.x;
  const int tid = threadIdx.x;
  float s1 = 0.f, s2 = 0.f;
  for (int p = tid; p < 2048; p += 256) {
    s1 += part[p * 256 + o];
    s2 += part[p * 256 + 128 + o];
  }
  __shared__ float r1[256], r2[256];
  r1[tid] = s1; r2[tid] = s2;
  __syncthreads();
  for (int s = 128; s >= 1; s >>= 1) {
    if (tid < s) { r1[tid] += r1[tid + s]; r2[tid] += r2[tid + s]; }
    __syncthreads();
  }
  if (tid == 0) {
    const float n = (float)(NBATCH * NPOINT * KNN_K);
    float mean = r1[0] / n;
    float var = r2[0] / n - mean * mean;
    float inv = rsqrtf(var + 1e-5f);
    float sc = gamma[o] * inv;
    stats[o] = sc;
    stats[128 + o] = beta[o] - mean * sc;
  }
}

// ---------------- Kernel 5: finalize out = relu(sel*sc + sh) ----------------
__global__ __launch_bounds__(256) void finalize_kernel(float* __restrict__ out_feat,
                                                       const float* __restrict__ mnbuf,
                                                       const float* __restrict__ stats) {
  const int i = blockIdx.x * 256 + threadIdx.x;
  const int o = i & 127;
  const float sc = stats[o];
  const float sh = stats[128 + o];
  const float mx = out_feat[i];
  const float mn = mnbuf[i];
  const float sel = (sc >= 0.f) ? mx : mn;
  out_feat[i] = fmaxf(sel * sc + sh, 0.f);
}

extern "C" void kernel_launch(void* const* d_in, const int* in_sizes, int n_in,
                              void* d_out, int out_size, void* d_ws, size_t ws_size,
                              hipStream_t stream) {
  const float* xyz = (const float*)d_in[0];
  const float* feat = (const float*)d_in[1];
  const float* W = (const float*)d_in[2];
  const float* gamma = (const float*)d_in[3];
  const float* beta = (const float*)d_in[4];
  float* out = (float*)d_out;

  int* cent = (int*)d_ws;
  int* knn = cent + NBATCH * NPOINT;
  float* part = (float*)(knn + NBATCH * NPOINT * KNN_K);
  float* stats = part + 2048 * 256;
  float* mnbuf = stats + 256;

  float* out_xyz = out;
  float* out_feat = out + NBATCH * NPOINT * 3;

  hipLaunchKernelGGL(fps_kernel, dim3(NBATCH), dim3(1024), 0, stream, xyz, cent);
  hipLaunchKernelGGL(knn_kernel, dim3(NBATCH * NPOINT), dim3(256), 0, stream,
                     xyz, cent, knn, out_xyz);
  hipLaunchKernelGGL(gemm_stats_kernel, dim3(2048), dim3(256), 0, stream,
                     feat, W, knn, part, out_feat, mnbuf);
  hipLaunchKernelGGL(bn_reduce_kernel, dim3(128), dim3(256), 0, stream,
                     part, gamma, beta, stats);
  hipLaunchKernelGGL(finalize_kernel, dim3(8192), dim3(256), 0, stream,
                     out_feat, mnbuf, stats);
}

// Round 8
// 2129.286 us; speedup vs baseline: 1.2892x; 1.0081x over previous
//
#include <hip/hip_runtime.h>
#include <stdint.h>

#define NPTS 8192
#define NBATCH 8
#define NPOINT 2048
#define KNN_K 16
#define CIN 64
#define COUT 128

typedef unsigned long long u64;
typedef unsigned int u32;

#define MAXU64(a, b) (((a) > (b)) ? (a) : (b))
#define MAXF64(a, b) fmax((a), (b))

// wave64 max-reduce of a positive-finite f64 key via DPP row_shr + row_bcast.
// Result valid in lane 63. Proven in rounds 4-7.
__device__ __forceinline__ double wave_max_f64(double v) {
#define DPPSTEP(C)                                                             \
  {                                                                            \
    u64 k = (u64)__double_as_longlong(v);                                      \
    u32 lo = (u32)k, hi = (u32)(k >> 32);                                      \
    u32 nlo = (u32)__builtin_amdgcn_update_dpp(0, (int)lo, C, 0xf, 0xf, true); \
    u32 nhi = (u32)__builtin_amdgcn_update_dpp(0, (int)hi, C, 0xf, 0xf, true); \
    double o = __longlong_as_double((long long)(((u64)nhi << 32) | nlo));      \
    v = fmax(v, o);                                                            \
  }
  DPPSTEP(0x111)
  DPPSTEP(0x112)
  DPPSTEP(0x114)
  DPPSTEP(0x118)
  DPPSTEP(0x142)
  DPPSTEP(0x143)
#undef DPPSTEP
  return v;
}

// wave64 max-reduce on exact u64 keys (for knn).
__device__ __forceinline__ u64 wave_max_u64(u64 k) {
  u32 lo = (u32)k, hi = (u32)(k >> 32);
#define DPPSTEP(C)                                                             \
  {                                                                            \
    u32 nlo = (u32)__builtin_amdgcn_update_dpp(0, (int)lo, C, 0xf, 0xf, true); \
    u32 nhi = (u32)__builtin_amdgcn_update_dpp(0, (int)hi, C, 0xf, 0xf, true); \
    u64 cur = ((u64)hi << 32) | lo;                                            \
    u64 oth = ((u64)nhi << 32) | nlo;                                          \
    if (oth > cur) { hi = nhi; lo = nlo; }                                     \
  }
  DPPSTEP(0x111)
  DPPSTEP(0x112)
  DPPSTEP(0x114)
  DPPSTEP(0x118)
  DPPSTEP(0x142)
  DPPSTEP(0x143)
#undef DPPSTEP
  return ((u64)hi << 32) | lo;
}

// wave64 min/max f32, invalid lanes keep own value (bound_ctrl=false).
__device__ __forceinline__ float wave_min_f32(float v) {
#define STEP(C)                                                                \
  {                                                                            \
    int o = __builtin_amdgcn_update_dpp((int)__float_as_uint(v),               \
                                        (int)__float_as_uint(v), C, 0xf, 0xf,  \
                                        false);                                \
    v = fminf(v, __uint_as_float((u32)o));                                     \
  }
  STEP(0x111) STEP(0x112) STEP(0x114) STEP(0x118) STEP(0x142) STEP(0x143)
#undef STEP
  return v;
}
__device__ __forceinline__ float wave_max_f32(float v) {
#define STEP(C)                                                                \
  {                                                                            \
    int o = __builtin_amdgcn_update_dpp((int)__float_as_uint(v),               \
                                        (int)__float_as_uint(v), C, 0xf, 0xf,  \
                                        false);                                \
    v = fmaxf(v, __uint_as_float((u32)o));                                     \
  }
  STEP(0x111) STEP(0x112) STEP(0x114) STEP(0x118) STEP(0x142) STEP(0x143)
#undef STEP
  return v;
}

__device__ __forceinline__ float bcast63(float v) {
  return __uint_as_float(
      (u32)__builtin_amdgcn_readlane((int)__float_as_uint(v), 63));
}

__device__ __forceinline__ u32 sp2(u32 v) {  // 2 bits -> bits 0,3
  return (v & 1u) | ((v & 2u) << 2);
}

// ---------------- Kernel 1: FPS, 8 waves, 2 register buckets per wave -------
// grid NBATCH, block 512. One-time: counting-sort points by 64-bin Morton
// code; wave w owns sorted slices [1024w,1024w+512) and [1024w+512,1024w+1024)
// in REGISTERS (8 pts/thread each) with per-slice true bboxes and per-slice
// cached wave-max keys (wave-uniform u64). Per iter: 2 bbox skip tests
// (bit-exact no-op skips, margin covers f32 rounding — proven r5-r7), update
// only dirty slices, post max(kc0,kc1), 1 barrier, resolve over 8 keys.
// Key = (dist_bits<<32)|((8191-orig)<<13)|pos : argmax with first-orig-index
// tie-break; pos bits only fetch coords, never affect the winner.
__global__ __launch_bounds__(512) void fps_kernel(const float* __restrict__ xyz,
                                                  int* __restrict__ cent) {
  const int b = blockIdx.x;
  const int tid = threadIdx.x;
  const int lane = tid & 63;
  const int wid = tid >> 6;  // 0..7
  const float* xb = xyz + (size_t)b * NPTS * 3;

  __shared__ float X[NPTS], Y[NPTS], Z[NPTS];
  __shared__ unsigned short O[NPTS];
  __shared__ float gred[8][6];
  __shared__ int cnt64[64], base64[64], cur64[64];
  __shared__ __align__(16) u64 kbuf[2][8];

  // ---- load 16 pts/thread + global bbox ----
  float lx[16], ly[16], lz[16];
  float xl = 3e38f, xh = -3e38f, yl = 3e38f, yh = -3e38f, zl = 3e38f, zh = -3e38f;
#pragma unroll
  for (int j = 0; j < 16; ++j) {
    int i = tid + 512 * j;
    float x = xb[i * 3 + 0], y = xb[i * 3 + 1], z = xb[i * 3 + 2];
    lx[j] = x; ly[j] = y; lz[j] = z;
    xl = fminf(xl, x); xh = fmaxf(xh, x);
    yl = fminf(yl, y); yh = fmaxf(yh, y);
    zl = fminf(zl, z); zh = fmaxf(zh, z);
  }
  xl = wave_min_f32(xl); xh = wave_max_f32(xh);
  yl = wave_min_f32(yl); yh = wave_max_f32(yh);
  zl = wave_min_f32(zl); zh = wave_max_f32(zh);
  if (lane == 63) {
    gred[wid][0] = xl; gred[wid][1] = xh; gred[wid][2] = yl;
    gred[wid][3] = yh; gred[wid][4] = zl; gred[wid][5] = zh;
  }
  if (tid < 64) { cnt64[tid] = 0; cur64[tid] = 0; }
  __syncthreads();
  float gx0 = gred[0][0], gx1 = gred[0][1], gy0 = gred[0][2];
  float gy1 = gred[0][3], gz0 = gred[0][4], gz1 = gred[0][5];
#pragma unroll
  for (int w = 1; w < 8; ++w) {
    gx0 = fminf(gx0, gred[w][0]); gx1 = fmaxf(gx1, gred[w][1]);
    gy0 = fminf(gy0, gred[w][2]); gy1 = fmaxf(gy1, gred[w][3]);
    gz0 = fminf(gz0, gred[w][4]); gz1 = fmaxf(gz1, gred[w][5]);
  }
  const float sx = 4.f / fmaxf((gx1 - gx0) * 1.0001f, 1e-20f);
  const float sy = 4.f / fmaxf((gy1 - gy0) * 1.0001f, 1e-20f);
  const float sz = 4.f / fmaxf((gz1 - gz0) * 1.0001f, 1e-20f);

  // ---- 64-bin Morton histogram ----
  int bin[16];
#pragma unroll
  for (int j = 0; j < 16; ++j) {
    u32 qx = (u32)min(3, max(0, (int)((lx[j] - gx0) * sx)));
    u32 qy = (u32)min(3, max(0, (int)((ly[j] - gy0) * sy)));
    u32 qz = (u32)min(3, max(0, (int)((lz[j] - gz0) * sz)));
    bin[j] = (int)((sp2(qx) << 2) | (sp2(qy) << 1) | sp2(qz));
    atomicAdd(&cnt64[bin[j]], 1);
  }
  __syncthreads();
  if (tid == 0) {
    int s = 0;
#pragma unroll
    for (int k = 0; k < 64; ++k) { base64[k] = s; s += cnt64[k]; }
  }
  __syncthreads();
  // ---- scatter into sorted SoA ----
#pragma unroll
  for (int j = 0; j < 16; ++j) {
    int i = tid + 512 * j;
    int pos = base64[bin[j]] + atomicAdd(&cur64[bin[j]], 1);
    X[pos] = lx[j]; Y[pos] = ly[j]; Z[pos] = lz[j];
    O[pos] = (unsigned short)i;
  }
  if (tid == 0) cent[b * NPOINT] = 0;
  __syncthreads();

  // ---- two 512-pt slices per wave into registers + per-slice bbox ----
  float pxA[8], pyA[8], pzA[8], dA[8];
  float pxB[8], pyB[8], pzB[8], dB[8];
  u32 kA[8], kB[8];
  float axl = 3e38f, axh = -3e38f, ayl = 3e38f, ayh = -3e38f, azl = 3e38f, azh = -3e38f;
#pragma unroll
  for (int j = 0; j < 8; ++j) {
    int p = wid * 1024 + lane + 64 * j;
    float x = X[p], y = Y[p], z = Z[p];
    pxA[j] = x; pyA[j] = y; pzA[j] = z;
    dA[j] = 1e10f;
    kA[j] = ((8191u - (u32)O[p]) << 13) | (u32)p;
    axl = fminf(axl, x); axh = fmaxf(axh, x);
    ayl = fminf(ayl, y); ayh = fmaxf(ayh, y);
    azl = fminf(azl, z); azh = fmaxf(azh, z);
  }
  const float Ax0 = bcast63(wave_min_f32(axl)), Ax1 = bcast63(wave_max_f32(axh));
  const float Ay0 = bcast63(wave_min_f32(ayl)), Ay1 = bcast63(wave_max_f32(ayh));
  const float Az0 = bcast63(wave_min_f32(azl)), Az1 = bcast63(wave_max_f32(azh));
  float bxl = 3e38f, bxh = -3e38f, byl = 3e38f, byh = -3e38f, bzl = 3e38f, bzh = -3e38f;
#pragma unroll
  for (int j = 0; j < 8; ++j) {
    int p = wid * 1024 + 512 + lane + 64 * j;
    float x = X[p], y = Y[p], z = Z[p];
    pxB[j] = x; pyB[j] = y; pzB[j] = z;
    dB[j] = 1e10f;
    kB[j] = ((8191u - (u32)O[p]) << 13) | (u32)p;
    bxl = fminf(bxl, x); bxh = fmaxf(bxh, x);
    byl = fminf(byl, y); byh = fmaxf(byh, y);
    bzl = fminf(bzl, z); bzh = fmaxf(bzh, z);
  }
  const float Bx0 = bcast63(wave_min_f32(bxl)), Bx1 = bcast63(wave_max_f32(bxh));
  const float By0 = bcast63(wave_min_f32(byl)), By1 = bcast63(wave_max_f32(byh));
  const float Bz0 = bcast63(wave_min_f32(bzl)), Bz1 = bcast63(wave_max_f32(bzh));

  float cx = xb[0], cy = xb[1], cz = xb[2];  // centroid 0 = point 0
  u64 kc0 = ((u64)__float_as_uint(1e10f) << 32);  // cached slice keys
  u64 kc1 = kc0;
  float dmax0 = 1e10f, dmax1 = 1e10f;

#define UPDATE_SLICE(PX, PY, PZ, DD, KK, KC, DM)                               \
  {                                                                            \
    double key[8];                                                             \
    _Pragma("unroll") for (int j = 0; j < 8; ++j) {                            \
      float dx = PX[j] - cx, dy = PY[j] - cy, dz = PZ[j] - cz;                 \
      float dd = dx * dx + dy * dy + dz * dz; /* same expr as rounds 1-7 */    \
      float t = fminf(DD[j], dd);                                              \
      DD[j] = t;                                                               \
      key[j] = __longlong_as_double(                                           \
          (long long)(((u64)__float_as_uint(t) << 32) | KK[j]));               \
    }                                                                          \
    _Pragma("unroll") for (int s = 1; s < 8; s <<= 1) {                        \
      _Pragma("unroll") for (int j = 0; j < 8; j += 2 * s)                     \
          key[j] = MAXF64(key[j], key[j + s]);                                 \
    }                                                                          \
    double wk = wave_max_f64(key[0]);                                          \
    u64 wkb = (u64)__double_as_longlong(wk);                                   \
    u32 hi_ = (u32)__builtin_amdgcn_readlane((int)(u32)(wkb >> 32), 63);       \
    u32 lo_ = (u32)__builtin_amdgcn_readlane((int)(u32)wkb, 63);               \
    KC = ((u64)hi_ << 32) | lo_;                                               \
    DM = __uint_as_float(hi_);                                                 \
  }

  for (int it = 1; it < NPOINT; ++it) {
    // per-slice exact skip tests (wave-uniform)
    float ax = fmaxf(fmaxf(Ax0 - cx, cx - Ax1), 0.f);
    float ay = fmaxf(fmaxf(Ay0 - cy, cy - Ay1), 0.f);
    float az = fmaxf(fmaxf(Az0 - cz, cz - Az1), 0.f);
    float LB0 = ax * ax + ay * ay + az * az;
    ax = fmaxf(fmaxf(Bx0 - cx, cx - Bx1), 0.f);
    ay = fmaxf(fmaxf(By0 - cy, cy - By1), 0.f);
    az = fmaxf(fmaxf(Bz0 - cz, cz - Bz1), 0.f);
    float LB1 = ax * ax + ay * ay + az * az;
    int dirty0 = __builtin_amdgcn_readfirstlane((LB0 > dmax0 * 1.00002f) ? 0 : 1);
    int dirty1 = __builtin_amdgcn_readfirstlane((LB1 > dmax1 * 1.00002f) ? 0 : 1);
    if (dirty0) UPDATE_SLICE(pxA, pyA, pzA, dA, kA, kc0, dmax0);
    if (dirty1) UPDATE_SLICE(pxB, pyB, pzB, dB, kB, kc1, dmax1);
    if (lane == 63) kbuf[it & 1][wid] = MAXU64(kc0, kc1);
    __syncthreads();  // the only barrier per iteration
    // resolve: 4 b128 broadcast reads + f64 max tree (all threads)
    const double2* kb = (const double2*)&kbuf[it & 1][0];
    double2 p0 = kb[0], p1 = kb[1], p2 = kb[2], p3 = kb[3];
    double m0 = MAXF64(p0.x, p0.y), m1 = MAXF64(p1.x, p1.y);
    double m2 = MAXF64(p2.x, p2.y), m3 = MAXF64(p3.x, p3.y);
    double best = MAXF64(MAXF64(m0, m1), MAXF64(m2, m3));
    u32 rlo = (u32)(u64)__double_as_longlong(best);
    u32 pos = rlo & 8191u;
    if (tid == 0) cent[b * NPOINT + it] = (int)(8191u - ((rlo >> 13) & 8191u));
    cx = X[pos]; cy = Y[pos]; cz = Z[pos];  // broadcast LDS reads
  }
#undef UPDATE_SLICE
}

// ---------------- Kernel 2: 16-NN per centroid + new_xyz gather ----------------
__global__ __launch_bounds__(256) void knn_kernel(const float* __restrict__ xyz,
                                                  const int* __restrict__ cent,
                                                  int* __restrict__ knn,
                                                  float* __restrict__ out_xyz) {
  const int pt = blockIdx.x;       // 0..16383
  const int b = pt >> 11;
  const int tid = threadIdx.x;
  const float* xb = xyz + (size_t)b * NPTS * 3;
  const int ci = cent[pt];
  const float mx = xb[ci * 3 + 0], my = xb[ci * 3 + 1], mz = xb[ci * 3 + 2];
  if (tid < 3) out_xyz[pt * 3 + tid] = xb[ci * 3 + tid];
  const float sm = mx * mx + my * my + mz * mz;

  float d[32];
  float lv = 3.0e38f;
  int lj = 0;
#pragma unroll
  for (int j = 0; j < 32; ++j) {
    int i = tid + 256 * j;
    float x = xb[i * 3 + 0], y = xb[i * 3 + 1], z = xb[i * 3 + 2];
    float dot = mx * x + my * y + mz * z;
    float sp = x * x + y * y + z * z;
    float dd = -2.0f * dot + sm + sp;   // same assoc as reference
    d[j] = dd;
    if (dd < lv) { lv = dd; lj = j; }
  }

  __shared__ __align__(16) u64 kbuf[2][4];
  const int lane = tid & 63;

  for (int p = 0; p < KNN_K; ++p) {
    u32 fb = __float_as_uint(lv);
    u32 mapped = (fb & 0x80000000u) ? ~fb : (fb | 0x80000000u);
    u32 idx = (u32)(tid + (lj << 8));
    u64 ik = ~(((u64)mapped << 32) | (u64)idx);
    u64 wk = wave_max_u64(ik);
    if (lane == 63) kbuf[p & 1][tid >> 6] = wk;
    __syncthreads();
    const ulonglong2* kb = (const ulonglong2*)&kbuf[p & 1][0];
    ulonglong2 q0 = kb[0], q1 = kb[1];
    u64 best = MAXU64(MAXU64(q0.x, q0.y), MAXU64(q1.x, q1.y));
    u32 widx = (u32)(~best);
    if (tid == 0) knn[pt * KNN_K + p] = (int)widx;
    if (tid == (int)(widx & 255u)) {
      int j0 = (int)(widx >> 8);
      float nlv = 3.0e38f;
      int nlj = 0;
#pragma unroll
      for (int j = 0; j < 32; ++j) {
        if (j == j0) d[j] = 3.0e38f;
        if (d[j] < nlv) { nlv = d[j]; nlj = j; }
      }
      lv = nlv; lj = nlj;
    }
  }
}

// ---------------- Kernel 3: gather+GEMM + BN partials + per-(pt,o) max/min ----------------
__global__ __launch_bounds__(256) void gemm_stats_kernel(const float* __restrict__ feat,
                                                         const float* __restrict__ W,
                                                         const int* __restrict__ knn,
                                                         float* __restrict__ part,
                                                         float* __restrict__ mxbuf,
                                                         float* __restrict__ mnbuf) {
  const int tid = threadIdx.x;
  const int o0 = (tid & 63) * 2;
  const int o1 = o0 + 1;
  const int grp = tid >> 6;
  __shared__ __align__(16) float g[128][CIN];
  __shared__ int kidx[128];
  __shared__ float sred[4][128];

  const int rowbase = blockIdx.x * 128;
  if (tid < 128) kidx[tid] = knn[rowbase + tid];

  float4 w0v[16], w1v[16];
  {
    const float4* wv0 = (const float4*)(W + (size_t)o0 * CIN);
    const float4* wv1 = (const float4*)(W + (size_t)o1 * CIN);
#pragma unroll
    for (int q = 0; q < 16; ++q) { w0v[q] = wv0[q]; w1v[q] = wv1[q]; }
  }
  __syncthreads();
#pragma unroll
  for (int s = 0; s < 8; ++s) {
    int v = tid + 256 * s;
    int row = v >> 4, q = v & 15;
    int gr = rowbase + row;
    int bb = gr >> 15;
    const float4* src = (const float4*)(feat + (size_t)(bb * NPTS + kidx[row]) * CIN);
    *((float4*)&g[row][q * 4]) = src[q];
  }
  __syncthreads();

  float s1_0 = 0.f, s2_0 = 0.f, s1_1 = 0.f, s2_1 = 0.f;
#pragma unroll
  for (int pp = 0; pp < 2; ++pp) {
    const int ptl = grp + pp * 4;
    float mx0 = -3.0e38f, mn0 = 3.0e38f, mx1 = -3.0e38f, mn1 = 3.0e38f;
#pragma unroll
    for (int k = 0; k < KNN_K; ++k) {
      const int row = ptl * 16 + k;
      float a0 = 0.f, a1 = 0.f;
#pragma unroll
      for (int q = 0; q < 16; ++q) {
        float4 a = *((const float4*)&g[row][q * 4]);
        a0 += w0v[q].x * a.x + w0v[q].y * a.y + w0v[q].z * a.z + w0v[q].w * a.w;
        a1 += w1v[q].x * a.x + w1v[q].y * a.y + w1v[q].z * a.z + w1v[q].w * a.w;
      }
      s1_0 += a0; s2_0 += a0 * a0; mx0 = fmaxf(mx0, a0); mn0 = fminf(mn0, a0);
      s1_1 += a1; s2_1 += a1 * a1; mx1 = fmaxf(mx1, a1); mn1 = fminf(mn1, a1);
    }
    const size_t pt = (size_t)blockIdx.x * 8 + ptl;
    mxbuf[pt * COUT + o0] = mx0;
    mxbuf[pt * COUT + o1] = mx1;
    mnbuf[pt * COUT + o0] = mn0;
    mnbuf[pt * COUT + o1] = mn1;
  }
  sred[grp][o0] = s1_0; sred[grp][o1] = s1_1;
  __syncthreads();
  if (tid < 128) {
    float t = sred[0][tid] + sred[1][tid] + sred[2][tid] + sred[3][tid];
    part[blockIdx.x * 256 + tid] = t;
  }
  __syncthreads();
  sred[grp][o0] = s2_0; sred[grp][o1] = s2_1;
  __syncthreads();
  if (tid < 128) {
    float t = sred[0][tid] + sred[1][tid] + sred[2][tid] + sred[3][tid];
    part[blockIdx.x * 256 + 128 + tid] = t;
  }
}

// ---------------- Kernel 4: reduce partials -> scale/shift per channel ----------------
__global__ __launch_bounds__(256) void bn_reduce_kernel(const float* __restrict__ part,
                                                        const float* __restrict__ gamma,
                                                        const float* __restrict__ beta,
                                                        float* __restrict__ stats) {
  const int o = blockIdx.x;
  const int tid = threadIdx.x;
  float s1 = 0.f, s2 = 0.f;
  for (int p = tid; p < 2048; p += 256) {
    s1 += part[p * 256 + o];
    s2 += part[p * 256 + 128 + o];
  }
  __shared__ float r1[256], r2[256];
  r1[tid] = s1; r2[tid] = s2;
  __syncthreads();
  for (int s = 128; s >= 1; s >>= 1) {
    if (tid < s) { r1[tid] += r1[tid + s]; r2[tid] += r2[tid + s]; }
    __syncthreads();
  }
  if (tid == 0) {
    const float n = (float)(NBATCH * NPOINT * KNN_K);
    float mean = r1[0] / n;
    float var = r2[0] / n - mean * mean;
    float inv = rsqrtf(var + 1e-5f);
    float sc = gamma[o] * inv;
    stats[o] = sc;
    stats[128 + o] = beta[o] - mean * sc;
  }
}

// ---------------- Kernel 5: finalize out = relu(sel*sc + sh) ----------------
__global__ __launch_bounds__(256) void finalize_kernel(float* __restrict__ out_feat,
                                                       const float* __restrict__ mnbuf,
                                                       const float* __restrict__ stats) {
  const int i = blockIdx.x * 256 + threadIdx.x;
  const int o = i & 127;
  const float sc = stats[o];
  const float sh = stats[128 + o];
  const float mx = out_feat[i];
  const float mn = mnbuf[i];
  const float sel = (sc >= 0.f) ? mx : mn;
  out_feat[i] = fmaxf(sel * sc + sh, 0.f);
}

extern "C" void kernel_launch(void* const* d_in, const int* in_sizes, int n_in,
                              void* d_out, int out_size, void* d_ws, size_t ws_size,
                              hipStream_t stream) {
  const float* xyz = (const float*)d_in[0];
  const float* feat = (const float*)d_in[1];
  const float* W = (const float*)d_in[2];
  const float* gamma = (const float*)d_in[3];
  const float* beta = (const float*)d_in[4];
  float* out = (float*)d_out;

  int* cent = (int*)d_ws;
  int* knn = cent + NBATCH * NPOINT;
  float* part = (float*)(knn + NBATCH * NPOINT * KNN_K);
  float* stats = part + 2048 * 256;
  float* mnbuf = stats + 256;

  float* out_xyz = out;
  float* out_feat = out + NBATCH * NPOINT * 3;

  hipLaunchKernelGGL(fps_kernel, dim3(NBATCH), dim3(512), 0, stream, xyz, cent);
  hipLaunchKernelGGL(knn_kernel, dim3(NBATCH * NPOINT), dim3(256), 0, stream,
                     xyz, cent, knn, out_xyz);
  hipLaunchKernelGGL(gemm_stats_kernel, dim3(2048), dim3(256), 0, stream,
                     feat, W, knn, part, out_feat, mnbuf);
  hipLaunchKernelGGL(bn_reduce_kernel, dim3(128), dim3(256), 0, stream,
                     part, gamma, beta, stats);
  hipLaunchKernelGGL(finalize_kernel, dim3(8192), dim3(256), 0, stream,
                     out_feat, mnbuf, stats);
}

// Round 9
// 1998.552 us; speedup vs baseline: 1.3736x; 1.0654x over previous
//
#include <hip/hip_runtime.h>
#include <stdint.h>

#define NPTS 8192
#define NBATCH 8
#define NPOINT 2048
#define KNN_K 16
#define CIN 64
#define COUT 128

typedef unsigned long long u64;
typedef unsigned int u32;

#define MAXU64(a, b) (((a) > (b)) ? (a) : (b))
#define MAXF64(a, b) fmax((a), (b))

// wave64 max-reduce of a positive-finite f64 key via DPP row_shr + row_bcast.
// Result valid in lane 63. Proven rounds 4-8.
__device__ __forceinline__ double wave_max_f64(double v) {
#define DPPSTEP(C)                                                             \
  {                                                                            \
    u64 k = (u64)__double_as_longlong(v);                                      \
    u32 lo = (u32)k, hi = (u32)(k >> 32);                                      \
    u32 nlo = (u32)__builtin_amdgcn_update_dpp(0, (int)lo, C, 0xf, 0xf, true); \
    u32 nhi = (u32)__builtin_amdgcn_update_dpp(0, (int)hi, C, 0xf, 0xf, true); \
    double o = __longlong_as_double((long long)(((u64)nhi << 32) | nlo));      \
    v = fmax(v, o);                                                            \
  }
  DPPSTEP(0x111)
  DPPSTEP(0x112)
  DPPSTEP(0x114)
  DPPSTEP(0x118)
  DPPSTEP(0x142)
  DPPSTEP(0x143)
#undef DPPSTEP
  return v;
}

// 8-lane (row_shr 1/2/4) f64 max: lane 7 of each 8-group holds max of lanes 0..7.
__device__ __forceinline__ double row8_max_f64(double v) {
#define DPPSTEP(C)                                                             \
  {                                                                            \
    u64 k = (u64)__double_as_longlong(v);                                      \
    u32 lo = (u32)k, hi = (u32)(k >> 32);                                      \
    u32 nlo = (u32)__builtin_amdgcn_update_dpp(0, (int)lo, C, 0xf, 0xf, true); \
    u32 nhi = (u32)__builtin_amdgcn_update_dpp(0, (int)hi, C, 0xf, 0xf, true); \
    double o = __longlong_as_double((long long)(((u64)nhi << 32) | nlo));      \
    v = fmax(v, o);                                                            \
  }
  DPPSTEP(0x111)
  DPPSTEP(0x112)
  DPPSTEP(0x114)
#undef DPPSTEP
  return v;
}

// wave64 max-reduce on exact u64 keys (for knn).
__device__ __forceinline__ u64 wave_max_u64(u64 k) {
  u32 lo = (u32)k, hi = (u32)(k >> 32);
#define DPPSTEP(C)                                                             \
  {                                                                            \
    u32 nlo = (u32)__builtin_amdgcn_update_dpp(0, (int)lo, C, 0xf, 0xf, true); \
    u32 nhi = (u32)__builtin_amdgcn_update_dpp(0, (int)hi, C, 0xf, 0xf, true); \
    u64 cur = ((u64)hi << 32) | lo;                                            \
    u64 oth = ((u64)nhi << 32) | nlo;                                          \
    if (oth > cur) { hi = nhi; lo = nlo; }                                     \
  }
  DPPSTEP(0x111)
  DPPSTEP(0x112)
  DPPSTEP(0x114)
  DPPSTEP(0x118)
  DPPSTEP(0x142)
  DPPSTEP(0x143)
#undef DPPSTEP
  return ((u64)hi << 32) | lo;
}

// wave64 min/max f32, invalid lanes keep own value (bound_ctrl=false).
__device__ __forceinline__ float wave_min_f32(float v) {
#define STEP(C)                                                                \
  {                                                                            \
    int o = __builtin_amdgcn_update_dpp((int)__float_as_uint(v),               \
                                        (int)__float_as_uint(v), C, 0xf, 0xf,  \
                                        false);                                \
    v = fminf(v, __uint_as_float((u32)o));                                     \
  }
  STEP(0x111) STEP(0x112) STEP(0x114) STEP(0x118) STEP(0x142) STEP(0x143)
#undef STEP
  return v;
}
__device__ __forceinline__ float wave_max_f32(float v) {
#define STEP(C)                                                                \
  {                                                                            \
    int o = __builtin_amdgcn_update_dpp((int)__float_as_uint(v),               \
                                        (int)__float_as_uint(v), C, 0xf, 0xf,  \
                                        false);                                \
    v = fmaxf(v, __uint_as_float((u32)o));                                     \
  }
  STEP(0x111) STEP(0x112) STEP(0x114) STEP(0x118) STEP(0x142) STEP(0x143)
#undef STEP
  return v;
}

__device__ __forceinline__ float bcast63(float v) {
  return __uint_as_float(
      (u32)__builtin_amdgcn_readlane((int)__float_as_uint(v), 63));
}

__device__ __forceinline__ u32 sp2(u32 v) {  // 2 bits -> bits 0,3
  return (v & 1u) | ((v & 2u) << 2);
}

// ---------------- Kernel 1: FPS, 8 waves, minimal per-iter DS traffic -------
// grid NBATCH, block 512. Morton counting-sort (64 bins) into LDS float4
// XYZ4[pos] = {x,y,z,orig_bits}; wave w owns sorted slice [1024w,1024w+1024)
// in REGISTERS (16 pts/thread) with its true bbox + bit-exact skip (r5-r8).
// Per iter DS ops/wave: 1 key write + 1 b64 key read + 1 b128 coord read.
// Key = (dist_bits<<32)|((8191-orig)<<13)|pos : argmax, first-orig tie-break.
__global__ __launch_bounds__(512) void fps_kernel(const float* __restrict__ xyz,
                                                  int* __restrict__ cent) {
  const int b = blockIdx.x;
  const int tid = threadIdx.x;
  const int lane = tid & 63;
  const int wid = tid >> 6;  // 0..7
  const float* xb = xyz + (size_t)b * NPTS * 3;

  __shared__ __align__(16) float4 XYZ4[NPTS];      // 128 KB
  __shared__ float gred[8][6];
  __shared__ int cnt64[64], base64[64], cur64[64];
  __shared__ __align__(16) double kbuf[2][8];

  // ---- load 16 pts/thread + global bbox ----
  float lx[16], ly[16], lz[16];
  float xl = 3e38f, xh = -3e38f, yl = 3e38f, yh = -3e38f, zl = 3e38f, zh = -3e38f;
#pragma unroll
  for (int j = 0; j < 16; ++j) {
    int i = tid + 512 * j;
    float x = xb[i * 3 + 0], y = xb[i * 3 + 1], z = xb[i * 3 + 2];
    lx[j] = x; ly[j] = y; lz[j] = z;
    xl = fminf(xl, x); xh = fmaxf(xh, x);
    yl = fminf(yl, y); yh = fmaxf(yh, y);
    zl = fminf(zl, z); zh = fmaxf(zh, z);
  }
  xl = wave_min_f32(xl); xh = wave_max_f32(xh);
  yl = wave_min_f32(yl); yh = wave_max_f32(yh);
  zl = wave_min_f32(zl); zh = wave_max_f32(zh);
  if (lane == 63) {
    gred[wid][0] = xl; gred[wid][1] = xh; gred[wid][2] = yl;
    gred[wid][3] = yh; gred[wid][4] = zl; gred[wid][5] = zh;
  }
  if (tid < 64) { cnt64[tid] = 0; cur64[tid] = 0; }
  __syncthreads();
  float gx0 = gred[0][0], gx1 = gred[0][1], gy0 = gred[0][2];
  float gy1 = gred[0][3], gz0 = gred[0][4], gz1 = gred[0][5];
#pragma unroll
  for (int w = 1; w < 8; ++w) {
    gx0 = fminf(gx0, gred[w][0]); gx1 = fmaxf(gx1, gred[w][1]);
    gy0 = fminf(gy0, gred[w][2]); gy1 = fmaxf(gy1, gred[w][3]);
    gz0 = fminf(gz0, gred[w][4]); gz1 = fmaxf(gz1, gred[w][5]);
  }
  const float sx = 4.f / fmaxf((gx1 - gx0) * 1.0001f, 1e-20f);
  const float sy = 4.f / fmaxf((gy1 - gy0) * 1.0001f, 1e-20f);
  const float sz = 4.f / fmaxf((gz1 - gz0) * 1.0001f, 1e-20f);

  // ---- 64-bin Morton histogram ----
  int bin[16];
#pragma unroll
  for (int j = 0; j < 16; ++j) {
    u32 qx = (u32)min(3, max(0, (int)((lx[j] - gx0) * sx)));
    u32 qy = (u32)min(3, max(0, (int)((ly[j] - gy0) * sy)));
    u32 qz = (u32)min(3, max(0, (int)((lz[j] - gz0) * sz)));
    bin[j] = (int)((sp2(qx) << 2) | (sp2(qy) << 1) | sp2(qz));
    atomicAdd(&cnt64[bin[j]], 1);
  }
  __syncthreads();
  if (tid == 0) {
    int s = 0;
#pragma unroll
    for (int k = 0; k < 64; ++k) { base64[k] = s; s += cnt64[k]; }
  }
  __syncthreads();
  // ---- scatter into sorted float4 SoA ----
#pragma unroll
  for (int j = 0; j < 16; ++j) {
    int i = tid + 512 * j;
    int pos = base64[bin[j]] + atomicAdd(&cur64[bin[j]], 1);
    XYZ4[pos] = make_float4(lx[j], ly[j], lz[j], __uint_as_float((u32)i));
  }
  if (tid == 0) cent[b * NPOINT] = 0;
  __syncthreads();

  // ---- own 1024-pt slice into registers + wave bbox ----
  float px[16], py[16], pz[16], dist[16];
  u32 klo[16];
  float axl = 3e38f, axh = -3e38f, ayl = 3e38f, ayh = -3e38f, azl = 3e38f, azh = -3e38f;
#pragma unroll
  for (int j = 0; j < 16; ++j) {
    int p = wid * 1024 + lane + 64 * j;
    float4 v = XYZ4[p];
    px[j] = v.x; py[j] = v.y; pz[j] = v.z;
    dist[j] = 1e10f;
    klo[j] = ((8191u - __float_as_uint(v.w)) << 13) | (u32)p;
    axl = fminf(axl, v.x); axh = fmaxf(axh, v.x);
    ayl = fminf(ayl, v.y); ayh = fmaxf(ayh, v.y);
    azl = fminf(azl, v.z); azh = fmaxf(azh, v.z);
  }
  const float bx0 = bcast63(wave_min_f32(axl)), bx1 = bcast63(wave_max_f32(axh));
  const float by0 = bcast63(wave_min_f32(ayl)), by1 = bcast63(wave_max_f32(ayh));
  const float bz0 = bcast63(wave_min_f32(azl)), bz1 = bcast63(wave_max_f32(azh));

  float cx = xb[0], cy = xb[1], cz = xb[2];  // centroid 0 = point 0
  float dmax = 1e10f;
  double prev_wk = 0.0;  // lane 63's copy is authoritative

  for (int it = 1; it < NPOINT; ++it) {
    // wave-local exact skip test (bit-exact no-op skip, proven r5-r8)
    float ax = fmaxf(fmaxf(bx0 - cx, cx - bx1), 0.f);
    float ay = fmaxf(fmaxf(by0 - cy, cy - by1), 0.f);
    float az = fmaxf(fmaxf(bz0 - cz, cz - bz1), 0.f);
    float LB = ax * ax + ay * ay + az * az;
    int skip = (LB > dmax * 1.00002f) ? 1 : 0;
    skip = __builtin_amdgcn_readfirstlane(skip);
    double wk;
    if (skip) {
      wk = prev_wk;
    } else {
      double key[16];
#pragma unroll
      for (int j = 0; j < 16; ++j) {
        float dx = px[j] - cx, dy = py[j] - cy, dz = pz[j] - cz;
        float dd = dx * dx + dy * dy + dz * dz;  // same expr as rounds 1-8
        float t = fminf(dist[j], dd);
        dist[j] = t;
        key[j] = __longlong_as_double(
            (long long)(((u64)__float_as_uint(t) << 32) | klo[j]));
      }
#pragma unroll
      for (int s = 1; s < 16; s <<= 1) {
#pragma unroll
        for (int j = 0; j < 16; j += 2 * s) key[j] = MAXF64(key[j], key[j + s]);
      }
      wk = wave_max_f64(key[0]);  // lane 63 owns the wave max
      prev_wk = wk;
      dmax = __uint_as_float((u32)__builtin_amdgcn_readlane(
          (int)(u32)(((u64)__double_as_longlong(wk)) >> 32), 63));
    }
    if (lane == 63) kbuf[it & 1][wid] = wk;  // 1 ds_write_b64
    __syncthreads();  // the only barrier per iteration
    // light resolve: 1 ds_read_b64 per lane + 3-step row8 DPP + readlane(7)
    double kv = kbuf[it & 1][lane & 7];
    kv = row8_max_f64(kv);
    u32 rlo = (u32)__builtin_amdgcn_readlane(
        (int)(u32)(u64)__double_as_longlong(kv), 7);
    u32 pos = rlo & 8191u;
    if (tid == 0) cent[b * NPOINT + it] = (int)(8191u - ((rlo >> 13) & 8191u));
    float4 c4 = XYZ4[pos];  // 1 ds_read_b128 broadcast
    cx = c4.x; cy = c4.y; cz = c4.z;
  }
}

// ---------------- Kernel 2: 16-NN per centroid + new_xyz gather ----------------
__global__ __launch_bounds__(256) void knn_kernel(const float* __restrict__ xyz,
                                                  const int* __restrict__ cent,
                                                  int* __restrict__ knn,
                                                  float* __restrict__ out_xyz) {
  const int pt = blockIdx.x;       // 0..16383
  const int b = pt >> 11;
  const int tid = threadIdx.x;
  const float* xb = xyz + (size_t)b * NPTS * 3;
  const int ci = cent[pt];
  const float mx = xb[ci * 3 + 0], my = xb[ci * 3 + 1], mz = xb[ci * 3 + 2];
  if (tid < 3) out_xyz[pt * 3 + tid] = xb[ci * 3 + tid];
  const float sm = mx * mx + my * my + mz * mz;

  float d[32];
  float lv = 3.0e38f;
  int lj = 0;
#pragma unroll
  for (int j = 0; j < 32; ++j) {
    int i = tid + 256 * j;
    float x = xb[i * 3 + 0], y = xb[i * 3 + 1], z = xb[i * 3 + 2];
    float dot = mx * x + my * y + mz * z;
    float sp = x * x + y * y + z * z;
    float dd = -2.0f * dot + sm + sp;   // same assoc as reference
    d[j] = dd;
    if (dd < lv) { lv = dd; lj = j; }
  }

  __shared__ __align__(16) u64 kbuf[2][4];
  const int lane = tid & 63;

  for (int p = 0; p < KNN_K; ++p) {
    u32 fb = __float_as_uint(lv);
    u32 mapped = (fb & 0x80000000u) ? ~fb : (fb | 0x80000000u);
    u32 idx = (u32)(tid + (lj << 8));
    u64 ik = ~(((u64)mapped << 32) | (u64)idx);
    u64 wk = wave_max_u64(ik);
    if (lane == 63) kbuf[p & 1][tid >> 6] = wk;
    __syncthreads();
    const ulonglong2* kb = (const ulonglong2*)&kbuf[p & 1][0];
    ulonglong2 q0 = kb[0], q1 = kb[1];
    u64 best = MAXU64(MAXU64(q0.x, q0.y), MAXU64(q1.x, q1.y));
    u32 widx = (u32)(~best);
    if (tid == 0) knn[pt * KNN_K + p] = (int)widx;
    if (tid == (int)(widx & 255u)) {
      int j0 = (int)(widx >> 8);
      float nlv = 3.0e38f;
      int nlj = 0;
#pragma unroll
      for (int j = 0; j < 32; ++j) {
        if (j == j0) d[j] = 3.0e38f;
        if (d[j] < nlv) { nlv = d[j]; nlj = j; }
      }
      lv = nlv; lj = nlj;
    }
  }
}

// ---------------- Kernel 3: gather+GEMM + BN partials + per-(pt,o) max/min ----------------
__global__ __launch_bounds__(256) void gemm_stats_kernel(const float* __restrict__ feat,
                                                         const float* __restrict__ W,
                                                         const int* __restrict__ knn,
                                                         float* __restrict__ part,
                                                         float* __restrict__ mxbuf,
                                                         float* __restrict__ mnbuf) {
  const int tid = threadIdx.x;
  const int o0 = (tid & 63) * 2;
  const int o1 = o0 + 1;
  const int grp = tid >> 6;
  __shared__ __align__(16) float g[128][CIN];
  __shared__ int kidx[128];
  __shared__ float sred[4][128];

  const int rowbase = blockIdx.x * 128;
  if (tid < 128) kidx[tid] = knn[rowbase + tid];

  float4 w0v[16], w1v[16];
  {
    const float4* wv0 = (const float4*)(W + (size_t)o0 * CIN);
    const float4* wv1 = (const float4*)(W + (size_t)o1 * CIN);
#pragma unroll
    for (int q = 0; q < 16; ++q) { w0v[q] = wv0[q]; w1v[q] = wv1[q]; }
  }
  __syncthreads();
#pragma unroll
  for (int s = 0; s < 8; ++s) {
    int v = tid + 256 * s;
    int row = v >> 4, q = v & 15;
    int gr = rowbase + row;
    int bb = gr >> 15;
    const float4* src = (const float4*)(feat + (size_t)(bb * NPTS + kidx[row]) * CIN);
    *((float4*)&g[row][q * 4]) = src[q];
  }
  __syncthreads();

  float s1_0 = 0.f, s2_0 = 0.f, s1_1 = 0.f, s2_1 = 0.f;
#pragma unroll
  for (int pp = 0; pp < 2; ++pp) {
    const int ptl = grp + pp * 4;
    float mx0 = -3.0e38f, mn0 = 3.0e38f, mx1 = -3.0e38f, mn1 = 3.0e38f;
#pragma unroll
    for (int k = 0; k < KNN_K; ++k) {
      const int row = ptl * 16 + k;
      float a0 = 0.f, a1 = 0.f;
#pragma unroll
      for (int q = 0; q < 16; ++q) {
        float4 a = *((const float4*)&g[row][q * 4]);
        a0 += w0v[q].x * a.x + w0v[q].y * a.y + w0v[q].z * a.z + w0v[q].w * a.w;
        a1 += w1v[q].x * a.x + w1v[q].y * a.y + w1v[q].z * a.z + w1v[q].w * a.w;
      }
      s1_0 += a0; s2_0 += a0 * a0; mx0 = fmaxf(mx0, a0); mn0 = fminf(mn0, a0);
      s1_1 += a1; s2_1 += a1 * a1; mx1 = fmaxf(mx1, a1); mn1 = fminf(mn1, a1);
    }
    const size_t pt = (size_t)blockIdx.x * 8 + ptl;
    mxbuf[pt * COUT + o0] = mx0;
    mxbuf[pt * COUT + o1] = mx1;
    mnbuf[pt * COUT + o0] = mn0;
    mnbuf[pt * COUT + o1] = mn1;
  }
  sred[grp][o0] = s1_0; sred[grp][o1] = s1_1;
  __syncthreads();
  if (tid < 128) {
    float t = sred[0][tid] + sred[1][tid] + sred[2][tid] + sred[3][tid];
    part[blockIdx.x * 256 + tid] = t;
  }
  __syncthreads();
  sred[grp][o0] = s2_0; sred[grp][o1] = s2_1;
  __syncthreads();
  if (tid < 128) {
    float t = sred[0][tid] + sred[1][tid] + sred[2][tid] + sred[3][tid];
    part[blockIdx.x * 256 + 128 + tid] = t;
  }
}

// ---------------- Kernel 4: reduce partials -> scale/shift per channel ----------------
__global__ __launch_bounds__(256) void bn_reduce_kernel(const float* __restrict__ part,
                                                        const float* __restrict__ gamma,
                                                        const float* __restrict__ beta,
                                                        float* __restrict__ stats) {
  const int o = blockIdx.x;
  const int tid = threadIdx.x;
  float s1 = 0.f, s2 = 0.f;
  for (int p = tid; p < 2048; p += 256) {
    s1 += part[p * 256 + o];
    s2 += part[p * 256 + 128 + o];
  }
  __shared__ float r1[256], r2[256];
  r1[tid] = s1; r2[tid] = s2;
  __syncthreads();
  for (int s = 128; s >= 1; s >>= 1) {
    if (tid < s) { r1[tid] += r1[tid + s]; r2[tid] += r2[tid + s]; }
    __syncthreads();
  }
  if (tid == 0) {
    const float n = (float)(NBATCH * NPOINT * KNN_K);
    float mean = r1[0] / n;
    float var = r2[0] / n - mean * mean;
    float inv = rsqrtf(var + 1e-5f);
    float sc = gamma[o] * inv;
    stats[o] = sc;
    stats[128 + o] = beta[o] - mean * sc;
  }
}

// ---------------- Kernel 5: finalize out = relu(sel*sc + sh) ----------------
__global__ __launch_bounds__(256) void finalize_kernel(float* __restrict__ out_feat,
                                                       const float* __restrict__ mnbuf,
                                                       const float* __restrict__ stats) {
  const int i = blockIdx.x * 256 + threadIdx.x;
  const int o = i & 127;
  const float sc = stats[o];
  const float sh = stats[128 + o];
  const float mx = out_feat[i];
  const float mn = mnbuf[i];
  const float sel = (sc >= 0.f) ? mx : mn;
  out_feat[i] = fmaxf(sel * sc + sh, 0.f);
}

extern "C" void kernel_launch(void* const* d_in, const int* in_sizes, int n_in,
                              void* d_out, int out_size, void* d_ws, size_t ws_size,
                              hipStream_t stream) {
  const float* xyz = (const float*)d_in[0];
  const float* feat = (const float*)d_in[1];
  const float* W = (const float*)d_in[2];
  const float* gamma = (const float*)d_in[3];
  const float* beta = (const float*)d_in[4];
  float* out = (float*)d_out;

  int* cent = (int*)d_ws;
  int* knn = cent + NBATCH * NPOINT;
  float* part = (float*)(knn + NBATCH * NPOINT * KNN_K);
  float* stats = part + 2048 * 256;
  float* mnbuf = stats + 256;

  float* out_xyz = out;
  float* out_feat = out + NBATCH * NPOINT * 3;

  hipLaunchKernelGGL(fps_kernel, dim3(NBATCH), dim3(512), 0, stream, xyz, cent);
  hipLaunchKernelGGL(knn_kernel, dim3(NBATCH * NPOINT), dim3(256), 0, stream,
                     xyz, cent, knn, out_xyz);
  hipLaunchKernelGGL(gemm_stats_kernel, dim3(2048), dim3(256), 0, stream,
                     feat, W, knn, part, out_feat, mnbuf);
  hipLaunchKernelGGL(bn_reduce_kernel, dim3(128), dim3(256), 0, stream,
                     part, gamma, beta, stats);
  hipLaunchKernelGGL(finalize_kernel, dim3(8192), dim3(256), 0, stream,
                     out_feat, mnbuf, stats);
}